// Round 13
// baseline (210.747 us; speedup 1.0000x reference)
//
#include <hip/hip_runtime.h>
#include <hip/hip_bf16.h>
#include <math.h>

#define BB 2
#define SS 2048
#define DD 1024
#define HH 16
#define HDIM 64

typedef unsigned short u16;
typedef __attribute__((ext_vector_type(8))) short bfrag;   // 8 bf16 = 4 VGPRs
typedef __attribute__((ext_vector_type(4))) float f32x4;

#define NEG_BIG (-1e30f)
// 1/sqrt(64) * log2(e): folded into Q so attention uses exp2 directly
#define QSCALE 0.18033688011112042f

__device__ __forceinline__ u16 f2u(float f) {
    unsigned int u = __builtin_bit_cast(unsigned int, f);
    u += 0x7fffu + ((u >> 16) & 1u);
    return (u16)(u >> 16);
}

__device__ __forceinline__ void async16(const u16* g, u16* l) {
    __builtin_amdgcn_global_load_lds((__attribute__((address_space(1))) void*)g,
                                     (__attribute__((address_space(3))) void*)l,
                                     16, 0, 0);
}

__device__ __forceinline__ f32x4 mfma16(bfrag a, bfrag b, f32x4 c) {
    return __builtin_amdgcn_mfma_f32_16x16x32_bf16(a, b, c, 0, 0, 0);
}

// ---------------------------------------------------------------------------
// prep: fused cvt_x + cvt_wT (unchanged).
// ---------------------------------------------------------------------------
__global__ __launch_bounds__(256) void prep_k(
    const float* __restrict__ x,  u16* __restrict__ xb,
    const float* __restrict__ wq, const float* __restrict__ wk,
    const float* __restrict__ wv, const float* __restrict__ wo,
    u16* __restrict__ wT)
{
    const int id = blockIdx.x;
    const int t = threadIdx.x;
    if (id < 2048) {
        int i = (id * 256 + t) * 8;
        float4 a = *(const float4*)(x + i);
        float4 b = *(const float4*)(x + i + 4);
        u16 o[8] = { f2u(a.x), f2u(a.y), f2u(a.z), f2u(a.w),
                     f2u(b.x), f2u(b.y), f2u(b.z), f2u(b.w) };
        *(uint4*)(xb + i) = *(uint4*)o;
        return;
    }
    const int wid = id - 2048;
    const int z = wid >> 8;
    const int kt = wid & 15, nt = (wid >> 4) & 15;
    const float* w = (z == 0) ? wq : (z == 1) ? wk : (z == 2) ? wv : wo;
    u16* o = wT + (size_t)z * DD * DD;
    __shared__ __align__(16) u16 T[64][72];
    const int k0 = kt * 64, n0 = nt * 64;
    {
        int kr = t >> 2, nb = (t & 3) * 16;
        const float4* s4 = (const float4*)(w + (size_t)(k0 + kr) * DD + n0 + nb);
        #pragma unroll
        for (int jj = 0; jj < 4; ++jj) {
            float4 v = s4[jj];
            T[kr][nb + jj*4 + 0] = f2u(v.x);
            T[kr][nb + jj*4 + 1] = f2u(v.y);
            T[kr][nb + jj*4 + 2] = f2u(v.z);
            T[kr][nb + jj*4 + 3] = f2u(v.w);
        }
    }
    __syncthreads();
    {
        int nr = t >> 2, kb = (t & 3) * 16;
        u16 tmp[16];
        #pragma unroll
        for (int j = 0; j < 16; ++j) tmp[j] = T[kb + j][nr];
        *(uint4*)(o + (size_t)(n0 + nr) * DD + k0 + kb)     = ((uint4*)tmp)[0];
        *(uint4*)(o + (size_t)(n0 + nr) * DD + k0 + kb + 8) = ((uint4*)tmp)[1];
    }
}

// ===========================================================================
// QKV GEMM (r12 verbatim): BM=128, BN=64, BK=64 -> 1536 blocks.
// ===========================================================================
__global__ __launch_bounds__(256) void gemm_qkv_k(
    const u16* __restrict__ xb, const u16* __restrict__ wT,
    u16* __restrict__ Qo, u16* __restrict__ Ko, u16* __restrict__ Vt)
{
    const u16* wTz = wT + (size_t)blockIdx.z * DD * DD;
    const float osc = (blockIdx.z == 0) ? QSCALE : 1.0f;

    __shared__ __align__(16) u16 As[128 * 64];   // 16 KB
    __shared__ __align__(16) u16 Bs[64 * 64];    // 8 KB

    const int t = threadIdx.x;
    const int m0 = blockIdx.x * 128, n0 = blockIdx.y * 64;
    const int lane15 = t & 15, quad = (t >> 4) & 3, wave = t >> 6;
    const int wm = wave & 1, wn = wave >> 1;

    int arow[4], acol[4];
    #pragma unroll
    for (int i = 0; i < 4; ++i) {
        int c = t + i * 256;
        arow[i] = c >> 3;
        acol[i] = (c & 7) ^ (arow[i] & 7);
    }
    const int br0 = t >> 3,         bs0 = t & 7;
    const int br1 = (t + 256) >> 3, bs1 = (t + 256) & 7;
    const int bc0 = bs0 ^ (br0 & 7);
    const int bc1 = bs1 ^ (br1 & 7);
    const int ldb = (t & 192) * 8;

    int aoff[4][2], boff[2][2];
    #pragma unroll
    for (int mi = 0; mi < 4; ++mi) {
        int r = wm * 64 + mi * 16 + lane15;
        #pragma unroll
        for (int kh = 0; kh < 2; ++kh)
            aoff[mi][kh] = (r * 8 + ((kh * 4 + quad) ^ (r & 7))) * 8;
    }
    #pragma unroll
    for (int ni = 0; ni < 2; ++ni) {
        int r = wn * 32 + ni * 16 + lane15;
        #pragma unroll
        for (int kh = 0; kh < 2; ++kh)
            boff[ni][kh] = (r * 8 + ((kh * 4 + quad) ^ (r & 7))) * 8;
    }

    f32x4 acc[4][2];
    #pragma unroll
    for (int mi = 0; mi < 4; ++mi)
        #pragma unroll
        for (int ni = 0; ni < 2; ++ni)
            acc[mi][ni] = (f32x4){0.f, 0.f, 0.f, 0.f};

    for (int it = 0; it < 16; ++it) {
        const int k0 = it * 64;
        #pragma unroll
        for (int i = 0; i < 4; ++i)
            async16(xb + (size_t)(m0 + arow[i]) * DD + k0 + acol[i] * 8,
                    As + ldb + i * 2048);
        async16(wTz + (size_t)(n0 + br0) * DD + k0 + bc0 * 8, Bs + ldb);
        async16(wTz + (size_t)(n0 + br1) * DD + k0 + bc1 * 8, Bs + ldb + 2048);
        __syncthreads();
        #pragma unroll
        for (int kh = 0; kh < 2; ++kh) {
            bfrag av[4], bv[2];
            #pragma unroll
            for (int mi = 0; mi < 4; ++mi) av[mi] = *(const bfrag*)(As + aoff[mi][kh]);
            #pragma unroll
            for (int ni = 0; ni < 2; ++ni) bv[ni] = *(const bfrag*)(Bs + boff[ni][kh]);
            #pragma unroll
            for (int mi = 0; mi < 4; ++mi)
                #pragma unroll
                for (int ni = 0; ni < 2; ++ni)
                    acc[mi][ni] = mfma16(av[mi], bv[ni], acc[mi][ni]);
        }
        __syncthreads();
    }

    const int h = n0 >> 6;
    const int bq = m0 >> 11;
    const int ms = m0 & (SS - 1);

    if (blockIdx.z != 2) {
        u16* out = (blockIdx.z == 0) ? Qo : Ko;
        u16* dst = out + (((size_t)(bq * HH + h)) * SS) * HDIM;
        #pragma unroll
        for (int mi = 0; mi < 4; ++mi) {
            #pragma unroll
            for (int r = 0; r < 4; ++r) {
                int s = ms + wm * 64 + mi * 16 + quad * 4 + r;
                #pragma unroll
                for (int ni = 0; ni < 2; ++ni) {
                    int hd = wn * 32 + ni * 16 + lane15;
                    dst[(size_t)s * HDIM + hd] = f2u(acc[mi][ni][r] * osc);
                }
            }
        }
    } else {
        u16* T = As;
        __syncthreads();
        #pragma unroll
        for (int mi = 0; mi < 4; ++mi)
            #pragma unroll
            for (int r = 0; r < 4; ++r) {
                int ml = wm * 64 + mi * 16 + quad * 4 + r;
                #pragma unroll
                for (int ni = 0; ni < 2; ++ni) {
                    int nl = wn * 32 + ni * 16 + lane15;
                    T[nl * 128 + (ml ^ ((nl & 7) << 4))] = f2u(acc[mi][ni][r]);
                }
            }
        __syncthreads();
        u16* dst = Vt + ((size_t)(bq * HH + h)) * (HDIM * SS);
        #pragma unroll
        for (int i = 0; i < 4; ++i) {
            int c = t + i * 256;
            int row = c >> 4;
            int mb  = (c & 15) * 8;
            uint4 val = *(const uint4*)&T[row * 128 + (mb ^ ((row & 7) << 4))];
            *(uint4*)(dst + (size_t)row * SS + ms + mb) = val;
        }
    }
}

// ---------------------------------------------------------------------------
// Out projection (r12 verbatim): BM=64, BN=64, BK=64 -> 1024 blocks.
// ---------------------------------------------------------------------------
__global__ __launch_bounds__(256) void gemm_out_k(
    const u16* __restrict__ ctxb, const u16* __restrict__ woT,
    const float* __restrict__ bo, float* __restrict__ out)
{
    __shared__ __align__(16) u16 As[64 * 64];
    __shared__ __align__(16) u16 Bs[64 * 64];

    const int t = threadIdx.x;
    const int m0 = blockIdx.x * 64, n0 = blockIdx.y * 64;
    const int lane15 = t & 15, quad = (t >> 4) & 3, wave = t >> 6;
    const int wm = wave & 1, wn = wave >> 1;

    const int br0 = t >> 3,         bs0 = t & 7;
    const int br1 = (t + 256) >> 3, bs1 = (t + 256) & 7;
    const int bc0 = bs0 ^ (br0 & 7);
    const int bc1 = bs1 ^ (br1 & 7);
    const int ldb = (t & 192) * 8;

    int aoff[2][2], boff[2][2];
    #pragma unroll
    for (int mi = 0; mi < 2; ++mi) {
        int r = wm * 32 + mi * 16 + lane15;
        #pragma unroll
        for (int kh = 0; kh < 2; ++kh)
            aoff[mi][kh] = (r * 8 + ((kh * 4 + quad) ^ (r & 7))) * 8;
    }
    #pragma unroll
    for (int ni = 0; ni < 2; ++ni) {
        int r = wn * 32 + ni * 16 + lane15;
        #pragma unroll
        for (int kh = 0; kh < 2; ++kh)
            boff[ni][kh] = (r * 8 + ((kh * 4 + quad) ^ (r & 7))) * 8;
    }

    f32x4 acc[2][2];
    #pragma unroll
    for (int mi = 0; mi < 2; ++mi)
        #pragma unroll
        for (int ni = 0; ni < 2; ++ni)
            acc[mi][ni] = (f32x4){0.f, 0.f, 0.f, 0.f};

    for (int it = 0; it < 16; ++it) {
        const int k0 = it * 64;
        async16(ctxb + (size_t)(m0 + br0) * DD + k0 + bc0 * 8, As + ldb);
        async16(ctxb + (size_t)(m0 + br1) * DD + k0 + bc1 * 8, As + ldb + 2048);
        async16(woT  + (size_t)(n0 + br0) * DD + k0 + bc0 * 8, Bs + ldb);
        async16(woT  + (size_t)(n0 + br1) * DD + k0 + bc1 * 8, Bs + ldb + 2048);
        __syncthreads();
        #pragma unroll
        for (int kh = 0; kh < 2; ++kh) {
            bfrag av[2], bv[2];
            #pragma unroll
            for (int mi = 0; mi < 2; ++mi) av[mi] = *(const bfrag*)(As + aoff[mi][kh]);
            #pragma unroll
            for (int ni = 0; ni < 2; ++ni) bv[ni] = *(const bfrag*)(Bs + boff[ni][kh]);
            #pragma unroll
            for (int mi = 0; mi < 2; ++mi)
                #pragma unroll
                for (int ni = 0; ni < 2; ++ni)
                    acc[mi][ni] = mfma16(av[mi], bv[ni], acc[mi][ni]);
        }
        __syncthreads();
    }

    float bias[2];
    #pragma unroll
    for (int ni = 0; ni < 2; ++ni)
        bias[ni] = bo[n0 + wn * 32 + ni * 16 + lane15];

    #pragma unroll
    for (int mi = 0; mi < 2; ++mi) {
        #pragma unroll
        for (int r = 0; r < 4; ++r) {
            int m = m0 + wm * 32 + mi * 16 + quad * 4 + r;
            #pragma unroll
            for (int ni = 0; ni < 2; ++ni) {
                int n = n0 + wn * 32 + ni * 16 + lane15;
                out[(size_t)m * DD + n] = acc[mi][ni][r] + bias[ni];
            }
        }
    }
}

// ===========================================================================
// Paired-tile MFMA flash attention. Block = (bh, j): Q-tiles qtA=j, qtB=31-j
// -> exactly 33 kv-tiles/block (perfect balance); K/V staged ONCE per pair.
// Fixed-max softmax (exp2), wave-uniform diag branch hoisted, K/V dbuf,
// 1 barrier/iter. LDS 48KB -> 3 blocks/CU.
// ===========================================================================
__device__ __forceinline__ void proc_tile(
    bfrag aq0, bfrag aq1, const u16* ksb, const u16* vsb, u16* QP,
    const int qoff[2], const int koff[4][2],
    f32x4 acc[4], float rsum[4],
    int kv0, int qgb, bool diag,
    int wave, int quad, int lane15)
{
    f32x4 s_acc[4];
    #pragma unroll
    for (int ni = 0; ni < 4; ++ni) s_acc[ni] = (f32x4){0.f, 0.f, 0.f, 0.f};
    #pragma unroll
    for (int ni = 0; ni < 4; ++ni)
        s_acc[ni] = mfma16(aq0, *(const bfrag*)(ksb + koff[ni][0]), s_acc[ni]);
    #pragma unroll
    for (int ni = 0; ni < 4; ++ni)
        s_acc[ni] = mfma16(aq1, *(const bfrag*)(ksb + koff[ni][1]), s_acc[ni]);

    const int prow = wave * 16 + quad * 4;
    if (diag) {                                   // wave-uniform branch
        #pragma unroll
        for (int ni = 0; ni < 4; ++ni) {
            int kvg = kv0 + ni * 16 + lane15;
            #pragma unroll
            for (int r = 0; r < 4; ++r) {
                float v = (kvg <= qgb + r) ? s_acc[ni][r] : NEG_BIG;
                float pw = exp2f(v);
                unsigned pu = __builtin_bit_cast(unsigned, pw);
                rsum[r] += __builtin_bit_cast(float, pu & 0xffff0000u);
                int row = prow + r, col = ni * 16 + lane15;
                QP[(row * 8 + ((col >> 3) ^ (row & 7))) * 8 + (col & 7)] = (u16)(pu >> 16);
            }
        }
    } else {
        #pragma unroll
        for (int ni = 0; ni < 4; ++ni) {
            #pragma unroll
            for (int r = 0; r < 4; ++r) {
                float pw = exp2f(s_acc[ni][r]);
                unsigned pu = __builtin_bit_cast(unsigned, pw);
                rsum[r] += __builtin_bit_cast(float, pu & 0xffff0000u);
                int row = prow + r, col = ni * 16 + lane15;
                QP[(row * 8 + ((col >> 3) ^ (row & 7))) * 8 + (col & 7)] = (u16)(pu >> 16);
            }
        }
    }
    #pragma unroll
    for (int kh = 0; kh < 2; ++kh) {
        bfrag ap = *(const bfrag*)(QP + qoff[kh]);
        #pragma unroll
        for (int nd = 0; nd < 4; ++nd)
            acc[nd] = mfma16(ap, *(const bfrag*)(vsb + koff[nd][kh]), acc[nd]);
    }
}

__global__ __launch_bounds__(256, 3) void attn_k(
    const u16* __restrict__ Q, const u16* __restrict__ K,
    const u16* __restrict__ Vt, u16* __restrict__ ctx)
{
    __shared__ __align__(16) u16 QPA[4096];       // Q_A staging, then P_A
    __shared__ __align__(16) u16 QPB[4096];       // Q_B staging, then P_B
    __shared__ __align__(16) u16 Ks[2][4096];
    __shared__ __align__(16) u16 Vs[2][4096];

    const int t = threadIdx.x;
    const int lane15 = t & 15, quad = (t >> 4) & 3, wave = t >> 6;
    const int bh = blockIdx.x;
    const int j  = blockIdx.y;                    // 0..15
    const int qtA = j, qtB = 31 - j;              // qtA < qtB always
    const int q0A = qtA * 64, q0B = qtB * 64;
    const int b = bh >> 4, h = bh & 15;

    const u16* Qb = Q  + (size_t)bh * SS * HDIM;
    const u16* Kb = K  + (size_t)bh * SS * HDIM;
    const u16* Vb = Vt + (size_t)bh * HDIM * SS;  // [64][2048]

    const int kr0 = t >> 3,         ks0 = t & 7;
    const int kr1 = (t + 256) >> 3, ks1 = (t + 256) & 7;
    const int kc0 = ks0 ^ (kr0 & 7);
    const int kc1 = ks1 ^ (kr1 & 7);
    const int ldst = (t & 192) * 8;

    // stage Q_A, Q_B, K0, V0
    async16(Qb + (size_t)(q0A + kr0) * HDIM + kc0 * 8, QPA + ldst);
    async16(Qb + (size_t)(q0A + kr1) * HDIM + kc1 * 8, QPA + ldst + 2048);
    async16(Qb + (size_t)(q0B + kr0) * HDIM + kc0 * 8, QPB + ldst);
    async16(Qb + (size_t)(q0B + kr1) * HDIM + kc1 * 8, QPB + ldst + 2048);
    async16(Kb + (size_t)kr0 * HDIM + kc0 * 8, &Ks[0][ldst]);
    async16(Kb + (size_t)kr1 * HDIM + kc1 * 8, &Ks[0][ldst + 2048]);
    async16(Vb + (size_t)kr0 * SS + kc0 * 8, &Vs[0][ldst]);
    async16(Vb + (size_t)kr1 * SS + kc1 * 8, &Vs[0][ldst + 2048]);

    const int qrow = wave * 16 + lane15;
    int qoff[2], koff[4][2];
    #pragma unroll
    for (int kh = 0; kh < 2; ++kh)
        qoff[kh] = (qrow * 8 + ((kh * 4 + quad) ^ (qrow & 7))) * 8;
    #pragma unroll
    for (int ni = 0; ni < 4; ++ni)
        #pragma unroll
        for (int kh = 0; kh < 2; ++kh) {
            int row = ni * 16 + lane15;
            koff[ni][kh] = (row * 8 + ((kh * 4 + quad) ^ (row & 7))) * 8;
        }

    __syncthreads();                  // drains Q_A/Q_B + K0/V0
    bfrag aqA[2], aqB[2];
    aqA[0] = *(const bfrag*)(QPA + qoff[0]);
    aqA[1] = *(const bfrag*)(QPA + qoff[1]);
    aqB[0] = *(const bfrag*)(QPB + qoff[0]);
    aqB[1] = *(const bfrag*)(QPB + qoff[1]);
    __syncthreads();                  // all waves done reading Q before P writes

    f32x4 acc_oA[4], acc_oB[4];
    float rsumA[4] = {0.f, 0.f, 0.f, 0.f};
    float rsumB[4] = {0.f, 0.f, 0.f, 0.f};
    #pragma unroll
    for (int nd = 0; nd < 4; ++nd) {
        acc_oA[nd] = (f32x4){0.f, 0.f, 0.f, 0.f};
        acc_oB[nd] = (f32x4){0.f, 0.f, 0.f, 0.f};
    }

    const int qgbA = q0A + wave * 16 + quad * 4;
    const int qgbB = q0B + wave * 16 + quad * 4;

    for (int kt = 0; kt <= qtB; ++kt) {
        if (kt < qtB) {               // prefetch kt+1 while computing kt
            const int nv0 = (kt + 1) * 64;
            const int pb = (kt + 1) & 1;
            async16(Kb + (size_t)(nv0 + kr0) * HDIM + kc0 * 8, &Ks[pb][ldst]);
            async16(Kb + (size_t)(nv0 + kr1) * HDIM + kc1 * 8, &Ks[pb][ldst + 2048]);
            async16(Vb + (size_t)kr0 * SS + nv0 + kc0 * 8, &Vs[pb][ldst]);
            async16(Vb + (size_t)kr1 * SS + nv0 + kc1 * 8, &Vs[pb][ldst + 2048]);
        }
        const u16* ksb = Ks[kt & 1];
        const u16* vsb = Vs[kt & 1];
        const int kv0 = kt * 64;

        proc_tile(aqB[0], aqB[1], ksb, vsb, QPB, qoff, koff,
                  acc_oB, rsumB, kv0, qgbB, kt == qtB, wave, quad, lane15);
        if (kt <= qtA)
            proc_tile(aqA[0], aqA[1], ksb, vsb, QPA, qoff, koff,
                      acc_oA, rsumA, kv0, qgbA, kt == qtA, wave, quad, lane15);
        __syncthreads();              // drains prefetch; releases buffers
    }

    // deferred row-sum reductions over the 16-lane col group
    #pragma unroll
    for (int off = 1; off < 16; off <<= 1)
        #pragma unroll
        for (int r = 0; r < 4; ++r) {
            rsumA[r] += __shfl_xor(rsumA[r], off, 64);
            rsumB[r] += __shfl_xor(rsumB[r], off, 64);
        }

    #pragma unroll
    for (int r = 0; r < 4; ++r) {
        int rloc = wave * 16 + quad * 4 + r;
        {
            float inv = 1.f / rsumA[r];
            size_t base = ((size_t)b * SS + q0A + rloc) * DD + h * HDIM;
            #pragma unroll
            for (int nd = 0; nd < 4; ++nd)
                ctx[base + nd * 16 + lane15] = f2u(acc_oA[nd][r] * inv);
        }
        {
            float inv = 1.f / rsumB[r];
            size_t base = ((size_t)b * SS + q0B + rloc) * DD + h * HDIM;
            #pragma unroll
            for (int nd = 0; nd < 4; ++nd)
                ctx[base + nd * 16 + lane15] = f2u(acc_oB[nd][r] * inv);
        }
    }
}

extern "C" void kernel_launch(void* const* d_in, const int* in_sizes, int n_in,
                              void* d_out, int out_size, void* d_ws, size_t ws_size,
                              hipStream_t stream) {
    const float* x  = (const float*)d_in[0];
    const float* wq = (const float*)d_in[1];
    const float* wk = (const float*)d_in[2];
    const float* wv = (const float*)d_in[3];
    const float* wo = (const float*)d_in[4];
    const float* bo = (const float*)d_in[5];
    float* out = (float*)d_out;

    char* ws = (char*)d_ws;
    const size_t MB8 = (size_t)8 * 1024 * 1024;
    u16* xb  = (u16*)(ws);             // 8MB; ctx reuses after qkv consumption
    u16* wT  = (u16*)(ws + MB8);       // 8MB
    u16* Qb  = (u16*)(ws + 2 * MB8);   // 8MB
    u16* Kb  = (u16*)(ws + 3 * MB8);   // 8MB
    u16* Vt  = (u16*)(ws + 4 * MB8);   // 8MB
    u16* ctxb = xb;

    prep_k    <<<3072, 256, 0, stream>>>(x, xb, wq, wk, wv, wo, wT);
    gemm_qkv_k<<<dim3(32, 16, 3), 256, 0, stream>>>(xb, wT, Qb, Kb, Vt);
    attn_k    <<<dim3(32, 16), 256, 0, stream>>>(Qb, Kb, Vt, ctxb);
    gemm_out_k<<<dim3(64, 16), 256, 0, stream>>>(ctxb, wT + (size_t)3 * DD * DD, bo, out);
}

// Round 14
// 178.960 us; speedup vs baseline: 1.1776x; 1.1776x over previous
//
#include <hip/hip_runtime.h>
#include <hip/hip_bf16.h>
#include <math.h>

#define BB 2
#define SS 2048
#define DD 1024
#define HH 16
#define HDIM 64

typedef unsigned short u16;
typedef __attribute__((ext_vector_type(8))) short bfrag;   // 8 bf16 = 4 VGPRs
typedef __attribute__((ext_vector_type(4))) float f32x4;

#define NEG_BIG (-1e30f)
// 1/sqrt(64) * log2(e): folded into Q so attention uses exp2 directly
#define QSCALE 0.18033688011112042f

__device__ __forceinline__ u16 f2u(float f) {
    unsigned int u = __builtin_bit_cast(unsigned int, f);
    u += 0x7fffu + ((u >> 16) & 1u);
    return (u16)(u >> 16);
}

__device__ __forceinline__ void async16(const u16* g, u16* l) {
    __builtin_amdgcn_global_load_lds((__attribute__((address_space(1))) void*)g,
                                     (__attribute__((address_space(3))) void*)l,
                                     16, 0, 0);
}

__device__ __forceinline__ f32x4 mfma16(bfrag a, bfrag b, f32x4 c) {
    return __builtin_amdgcn_mfma_f32_16x16x32_bf16(a, b, c, 0, 0, 0);
}

// ---------------------------------------------------------------------------
// prep: fused cvt_x + cvt_wT (r12 verbatim).
// ---------------------------------------------------------------------------
__global__ __launch_bounds__(256) void prep_k(
    const float* __restrict__ x,  u16* __restrict__ xb,
    const float* __restrict__ wq, const float* __restrict__ wk,
    const float* __restrict__ wv, const float* __restrict__ wo,
    u16* __restrict__ wT)
{
    const int id = blockIdx.x;
    const int t = threadIdx.x;
    if (id < 2048) {
        int i = (id * 256 + t) * 8;
        float4 a = *(const float4*)(x + i);
        float4 b = *(const float4*)(x + i + 4);
        u16 o[8] = { f2u(a.x), f2u(a.y), f2u(a.z), f2u(a.w),
                     f2u(b.x), f2u(b.y), f2u(b.z), f2u(b.w) };
        *(uint4*)(xb + i) = *(uint4*)o;
        return;
    }
    const int wid = id - 2048;
    const int z = wid >> 8;
    const int kt = wid & 15, nt = (wid >> 4) & 15;
    const float* w = (z == 0) ? wq : (z == 1) ? wk : (z == 2) ? wv : wo;
    u16* o = wT + (size_t)z * DD * DD;
    __shared__ __align__(16) u16 T[64][72];
    const int k0 = kt * 64, n0 = nt * 64;
    {
        int kr = t >> 2, nb = (t & 3) * 16;
        const float4* s4 = (const float4*)(w + (size_t)(k0 + kr) * DD + n0 + nb);
        #pragma unroll
        for (int jj = 0; jj < 4; ++jj) {
            float4 v = s4[jj];
            T[kr][nb + jj*4 + 0] = f2u(v.x);
            T[kr][nb + jj*4 + 1] = f2u(v.y);
            T[kr][nb + jj*4 + 2] = f2u(v.z);
            T[kr][nb + jj*4 + 3] = f2u(v.w);
        }
    }
    __syncthreads();
    {
        int nr = t >> 2, kb = (t & 3) * 16;
        u16 tmp[16];
        #pragma unroll
        for (int j = 0; j < 16; ++j) tmp[j] = T[kb + j][nr];
        *(uint4*)(o + (size_t)(n0 + nr) * DD + k0 + kb)     = ((uint4*)tmp)[0];
        *(uint4*)(o + (size_t)(n0 + nr) * DD + k0 + kb + 8) = ((uint4*)tmp)[1];
    }
}

// ===========================================================================
// QKV GEMM (r12 verbatim): BM=128, BN=64, BK=64 -> 1536 blocks.
// ===========================================================================
__global__ __launch_bounds__(256) void gemm_qkv_k(
    const u16* __restrict__ xb, const u16* __restrict__ wT,
    u16* __restrict__ Qo, u16* __restrict__ Ko, u16* __restrict__ Vt)
{
    const u16* wTz = wT + (size_t)blockIdx.z * DD * DD;
    const float osc = (blockIdx.z == 0) ? QSCALE : 1.0f;

    __shared__ __align__(16) u16 As[128 * 64];   // 16 KB
    __shared__ __align__(16) u16 Bs[64 * 64];    // 8 KB

    const int t = threadIdx.x;
    const int m0 = blockIdx.x * 128, n0 = blockIdx.y * 64;
    const int lane15 = t & 15, quad = (t >> 4) & 3, wave = t >> 6;
    const int wm = wave & 1, wn = wave >> 1;

    int arow[4], acol[4];
    #pragma unroll
    for (int i = 0; i < 4; ++i) {
        int c = t + i * 256;
        arow[i] = c >> 3;
        acol[i] = (c & 7) ^ (arow[i] & 7);
    }
    const int br0 = t >> 3,         bs0 = t & 7;
    const int br1 = (t + 256) >> 3, bs1 = (t + 256) & 7;
    const int bc0 = bs0 ^ (br0 & 7);
    const int bc1 = bs1 ^ (br1 & 7);
    const int ldb = (t & 192) * 8;

    int aoff[4][2], boff[2][2];
    #pragma unroll
    for (int mi = 0; mi < 4; ++mi) {
        int r = wm * 64 + mi * 16 + lane15;
        #pragma unroll
        for (int kh = 0; kh < 2; ++kh)
            aoff[mi][kh] = (r * 8 + ((kh * 4 + quad) ^ (r & 7))) * 8;
    }
    #pragma unroll
    for (int ni = 0; ni < 2; ++ni) {
        int r = wn * 32 + ni * 16 + lane15;
        #pragma unroll
        for (int kh = 0; kh < 2; ++kh)
            boff[ni][kh] = (r * 8 + ((kh * 4 + quad) ^ (r & 7))) * 8;
    }

    f32x4 acc[4][2];
    #pragma unroll
    for (int mi = 0; mi < 4; ++mi)
        #pragma unroll
        for (int ni = 0; ni < 2; ++ni)
            acc[mi][ni] = (f32x4){0.f, 0.f, 0.f, 0.f};

    for (int it = 0; it < 16; ++it) {
        const int k0 = it * 64;
        #pragma unroll
        for (int i = 0; i < 4; ++i)
            async16(xb + (size_t)(m0 + arow[i]) * DD + k0 + acol[i] * 8,
                    As + ldb + i * 2048);
        async16(wTz + (size_t)(n0 + br0) * DD + k0 + bc0 * 8, Bs + ldb);
        async16(wTz + (size_t)(n0 + br1) * DD + k0 + bc1 * 8, Bs + ldb + 2048);
        __syncthreads();
        #pragma unroll
        for (int kh = 0; kh < 2; ++kh) {
            bfrag av[4], bv[2];
            #pragma unroll
            for (int mi = 0; mi < 4; ++mi) av[mi] = *(const bfrag*)(As + aoff[mi][kh]);
            #pragma unroll
            for (int ni = 0; ni < 2; ++ni) bv[ni] = *(const bfrag*)(Bs + boff[ni][kh]);
            #pragma unroll
            for (int mi = 0; mi < 4; ++mi)
                #pragma unroll
                for (int ni = 0; ni < 2; ++ni)
                    acc[mi][ni] = mfma16(av[mi], bv[ni], acc[mi][ni]);
        }
        __syncthreads();
    }

    const int h = n0 >> 6;
    const int bq = m0 >> 11;
    const int ms = m0 & (SS - 1);

    if (blockIdx.z != 2) {
        u16* out = (blockIdx.z == 0) ? Qo : Ko;
        u16* dst = out + (((size_t)(bq * HH + h)) * SS) * HDIM;
        #pragma unroll
        for (int mi = 0; mi < 4; ++mi) {
            #pragma unroll
            for (int r = 0; r < 4; ++r) {
                int s = ms + wm * 64 + mi * 16 + quad * 4 + r;
                #pragma unroll
                for (int ni = 0; ni < 2; ++ni) {
                    int hd = wn * 32 + ni * 16 + lane15;
                    dst[(size_t)s * HDIM + hd] = f2u(acc[mi][ni][r] * osc);
                }
            }
        }
    } else {
        u16* T = As;
        __syncthreads();
        #pragma unroll
        for (int mi = 0; mi < 4; ++mi)
            #pragma unroll
            for (int r = 0; r < 4; ++r) {
                int ml = wm * 64 + mi * 16 + quad * 4 + r;
                #pragma unroll
                for (int ni = 0; ni < 2; ++ni) {
                    int nl = wn * 32 + ni * 16 + lane15;
                    T[nl * 128 + (ml ^ ((nl & 7) << 4))] = f2u(acc[mi][ni][r]);
                }
            }
        __syncthreads();
        u16* dst = Vt + ((size_t)(bq * HH + h)) * (HDIM * SS);
        #pragma unroll
        for (int i = 0; i < 4; ++i) {
            int c = t + i * 256;
            int row = c >> 4;
            int mb  = (c & 15) * 8;
            uint4 val = *(const uint4*)&T[row * 128 + (mb ^ ((row & 7) << 4))];
            *(uint4*)(dst + (size_t)row * SS + ms + mb) = val;
        }
    }
}

// ---------------------------------------------------------------------------
// Out projection: BM=64, BN=64, BK=128 (two 64-halves, same 8-chunk swizzle)
// -> 16 MFMA/barrier, 8 iters, LDS 32KB. Fused bias, fp32 out.
// ---------------------------------------------------------------------------
__global__ __launch_bounds__(256) void gemm_out_k(
    const u16* __restrict__ ctxb, const u16* __restrict__ woT,
    const float* __restrict__ bo, float* __restrict__ out)
{
    __shared__ __align__(16) u16 As[2][4096];    // [k-half][64x64]
    __shared__ __align__(16) u16 Bs[2][4096];

    const int t = threadIdx.x;
    const int m0 = blockIdx.x * 64, n0 = blockIdx.y * 64;
    const int lane15 = t & 15, quad = (t >> 4) & 3, wave = t >> 6;
    const int wm = wave & 1, wn = wave >> 1;

    const int br0 = t >> 3,         bs0 = t & 7;
    const int br1 = (t + 256) >> 3, bs1 = (t + 256) & 7;
    const int bc0 = bs0 ^ (br0 & 7);
    const int bc1 = bs1 ^ (br1 & 7);
    const int ldb = (t & 192) * 8;

    int aoff[2][2], boff[2][2];
    #pragma unroll
    for (int mi = 0; mi < 2; ++mi) {
        int r = wm * 32 + mi * 16 + lane15;
        #pragma unroll
        for (int kh = 0; kh < 2; ++kh)
            aoff[mi][kh] = (r * 8 + ((kh * 4 + quad) ^ (r & 7))) * 8;
    }
    #pragma unroll
    for (int ni = 0; ni < 2; ++ni) {
        int r = wn * 32 + ni * 16 + lane15;
        #pragma unroll
        for (int kh = 0; kh < 2; ++kh)
            boff[ni][kh] = (r * 8 + ((kh * 4 + quad) ^ (r & 7))) * 8;
    }

    f32x4 acc[2][2];
    #pragma unroll
    for (int mi = 0; mi < 2; ++mi)
        #pragma unroll
        for (int ni = 0; ni < 2; ++ni)
            acc[mi][ni] = (f32x4){0.f, 0.f, 0.f, 0.f};

    for (int it = 0; it < 8; ++it) {
        const int k0 = it * 128;
        #pragma unroll
        for (int hh = 0; hh < 2; ++hh) {
            const int kh64 = k0 + hh * 64;
            async16(ctxb + (size_t)(m0 + br0) * DD + kh64 + bc0 * 8, &As[hh][ldb]);
            async16(ctxb + (size_t)(m0 + br1) * DD + kh64 + bc1 * 8, &As[hh][ldb + 2048]);
            async16(woT  + (size_t)(n0 + br0) * DD + kh64 + bc0 * 8, &Bs[hh][ldb]);
            async16(woT  + (size_t)(n0 + br1) * DD + kh64 + bc1 * 8, &Bs[hh][ldb + 2048]);
        }
        __syncthreads();
        #pragma unroll
        for (int hh = 0; hh < 2; ++hh) {
            #pragma unroll
            for (int kh = 0; kh < 2; ++kh) {
                bfrag av[2], bv[2];
                #pragma unroll
                for (int mi = 0; mi < 2; ++mi) av[mi] = *(const bfrag*)&As[hh][aoff[mi][kh]];
                #pragma unroll
                for (int ni = 0; ni < 2; ++ni) bv[ni] = *(const bfrag*)&Bs[hh][boff[ni][kh]];
                #pragma unroll
                for (int mi = 0; mi < 2; ++mi)
                    #pragma unroll
                    for (int ni = 0; ni < 2; ++ni)
                        acc[mi][ni] = mfma16(av[mi], bv[ni], acc[mi][ni]);
            }
        }
        __syncthreads();
    }

    float bias[2];
    #pragma unroll
    for (int ni = 0; ni < 2; ++ni)
        bias[ni] = bo[n0 + wn * 32 + ni * 16 + lane15];

    #pragma unroll
    for (int mi = 0; mi < 2; ++mi) {
        #pragma unroll
        for (int r = 0; r < 4; ++r) {
            int m = m0 + wm * 32 + mi * 16 + quad * 4 + r;
            #pragma unroll
            for (int ni = 0; ni < 2; ++ni) {
                int n = n0 + wn * 32 + ni * 16 + lane15;
                out[(size_t)m * DD + n] = acc[mi][ni][r] + bias[ni];
            }
        }
    }
}

// ===========================================================================
// MFMA flash attention (r12 structure verbatim) + balanced qt interleave:
// y -> qt = 8L + (L odd ? 7-p : p), L=y>>3, p=y&7 -- under linear round-robin
// dispatch every CU's 4 resident blocks sum to exactly 66 kv-tiles.
// ===========================================================================
__global__ __launch_bounds__(256, 4) void attn_k(
    const u16* __restrict__ Q, const u16* __restrict__ K,
    const u16* __restrict__ Vt, u16* __restrict__ ctx)
{
    __shared__ __align__(16) u16 QP[64 * 64];
    __shared__ __align__(16) u16 Ks[2][64 * 64];
    __shared__ __align__(16) u16 Vs[2][64 * 64];
    const int t = threadIdx.x;
    const int lane15 = t & 15, quad = (t >> 4) & 3, wave = t >> 6;
    const int bh = blockIdx.x;
    const int y = (int)blockIdx.y;
    const int L = y >> 3, p = y & 7;
    const int qt = L * 8 + ((L & 1) ? (7 - p) : p);   // balanced interleave
    const int q0 = qt * 64;
    const int b = bh >> 4, h = bh & 15;
    const u16* Qb = Q  + (size_t)bh * SS * HDIM;
    const u16* Kb = K  + (size_t)bh * SS * HDIM;
    const u16* Vb = Vt + (size_t)bh * HDIM * SS;
    const int kr0 = t >> 3,         ks0 = t & 7;
    const int kr1 = (t + 256) >> 3, ks1 = (t + 256) & 7;
    const int kc0 = ks0 ^ (kr0 & 7);
    const int kc1 = ks1 ^ (kr1 & 7);
    const int ldst = (t & 192) * 8;
    async16(Qb + (size_t)(q0 + kr0) * HDIM + kc0 * 8, QP + ldst);
    async16(Qb + (size_t)(q0 + kr1) * HDIM + kc1 * 8, QP + ldst + 2048);
    async16(Kb + (size_t)kr0 * HDIM + kc0 * 8, &Ks[0][ldst]);
    async16(Kb + (size_t)kr1 * HDIM + kc1 * 8, &Ks[0][ldst + 2048]);
    async16(Vb + (size_t)kr0 * SS + kc0 * 8, &Vs[0][ldst]);
    async16(Vb + (size_t)kr1 * SS + kc1 * 8, &Vs[0][ldst + 2048]);
    const int qrow = wave * 16 + lane15;
    int qoff[2], koff[4][2];
    #pragma unroll
    for (int kh = 0; kh < 2; ++kh)
        qoff[kh] = (qrow * 8 + ((kh * 4 + quad) ^ (qrow & 7))) * 8;
    #pragma unroll
    for (int ni = 0; ni < 4; ++ni)
        #pragma unroll
        for (int kh = 0; kh < 2; ++kh) {
            int row = ni * 16 + lane15;
            koff[ni][kh] = (row * 8 + ((kh * 4 + quad) ^ (row & 7))) * 8;
        }
    __syncthreads();
    bfrag aq[2];
    aq[0] = *(const bfrag*)(QP + qoff[0]);
    aq[1] = *(const bfrag*)(QP + qoff[1]);
    __syncthreads();
    f32x4 acc_o[4];
    float rsum[4] = {0.f, 0.f, 0.f, 0.f};
    #pragma unroll
    for (int nd = 0; nd < 4; ++nd) acc_o[nd] = (f32x4){0.f, 0.f, 0.f, 0.f};
    const int qgb = q0 + wave * 16 + quad * 4;
    for (int kt = 0; kt <= qt; ++kt) {
        if (kt < qt) {
            const int nv0 = (kt + 1) * 64;
            const int pb = (kt + 1) & 1;
            async16(Kb + (size_t)(nv0 + kr0) * HDIM + kc0 * 8, &Ks[pb][ldst]);
            async16(Kb + (size_t)(nv0 + kr1) * HDIM + kc1 * 8, &Ks[pb][ldst + 2048]);
            async16(Vb + (size_t)kr0 * SS + nv0 + kc0 * 8, &Vs[pb][ldst]);
            async16(Vb + (size_t)kr1 * SS + nv0 + kc1 * 8, &Vs[pb][ldst + 2048]);
        }
        const int cb = kt & 1;
        const int kv0 = kt * 64;
        f32x4 s_acc[4];
        #pragma unroll
        for (int ni = 0; ni < 4; ++ni) s_acc[ni] = (f32x4){0.f, 0.f, 0.f, 0.f};
        #pragma unroll
        for (int kh = 0; kh < 2; ++kh)
            #pragma unroll
            for (int ni = 0; ni < 4; ++ni)
                s_acc[ni] = mfma16(aq[kh], *(const bfrag*)&Ks[cb][koff[ni][kh]], s_acc[ni]);
        const bool diag = (kt == qt);
        #pragma unroll
        for (int ni = 0; ni < 4; ++ni) {
            int kvg = kv0 + ni * 16 + lane15;
            #pragma unroll
            for (int r = 0; r < 4; ++r) {
                float v = s_acc[ni][r];
                if (diag && (kvg > qgb + r)) v = NEG_BIG;
                float pw = exp2f(v);
                unsigned pu = __builtin_bit_cast(unsigned, pw);
                rsum[r] += __builtin_bit_cast(float, pu & 0xffff0000u);
                int row = wave * 16 + quad * 4 + r;
                int col = ni * 16 + lane15;
                QP[(row * 8 + ((col >> 3) ^ (row & 7))) * 8 + (col & 7)] = (u16)(pu >> 16);
            }
        }
        #pragma unroll
        for (int kh = 0; kh < 2; ++kh) {
            bfrag ap = *(const bfrag*)(QP + qoff[kh]);
            #pragma unroll
            for (int nd = 0; nd < 4; ++nd)
                acc_o[nd] = mfma16(ap, *(const bfrag*)&Vs[cb][koff[nd][kh]], acc_o[nd]);
        }
        __syncthreads();
    }
    #pragma unroll
    for (int off = 1; off < 16; off <<= 1)
        #pragma unroll
        for (int r = 0; r < 4; ++r)
            rsum[r] += __shfl_xor(rsum[r], off, 64);
    #pragma unroll
    for (int r = 0; r < 4; ++r) {
        float inv = 1.f / rsum[r];
        int srow = q0 + wave * 16 + quad * 4 + r;
        size_t base = ((size_t)b * SS + srow) * DD + h * HDIM;
        #pragma unroll
        for (int nd = 0; nd < 4; ++nd)
            ctx[base + nd * 16 + lane15] = f2u(acc_o[nd][r] * inv);
    }
}

extern "C" void kernel_launch(void* const* d_in, const int* in_sizes, int n_in,
                              void* d_out, int out_size, void* d_ws, size_t ws_size,
                              hipStream_t stream) {
    const float* x  = (const float*)d_in[0];
    const float* wq = (const float*)d_in[1];
    const float* wk = (const float*)d_in[2];
    const float* wv = (const float*)d_in[3];
    const float* wo = (const float*)d_in[4];
    const float* bo = (const float*)d_in[5];
    float* out = (float*)d_out;

    char* ws = (char*)d_ws;
    const size_t MB8 = (size_t)8 * 1024 * 1024;
    u16* xb  = (u16*)(ws);             // 8MB; ctx reuses after qkv consumption
    u16* wT  = (u16*)(ws + MB8);       // 8MB
    u16* Qb  = (u16*)(ws + 2 * MB8);   // 8MB
    u16* Kb  = (u16*)(ws + 3 * MB8);   // 8MB
    u16* Vt  = (u16*)(ws + 4 * MB8);   // 8MB
    u16* ctxb = xb;

    prep_k    <<<3072, 256, 0, stream>>>(x, xb, wq, wk, wv, wo, wT);
    gemm_qkv_k<<<dim3(32, 16, 3), 256, 0, stream>>>(xb, wT, Qb, Kb, Vt);
    attn_k    <<<dim3(32, 32), 256, 0, stream>>>(Qb, Kb, Vt, ctxb);
    gemm_out_k<<<dim3(64, 16), 256, 0, stream>>>(ctxb, wT + (size_t)3 * DD * DD, bo, out);
}

// Round 15
// 176.152 us; speedup vs baseline: 1.1964x; 1.0159x over previous
//
#include <hip/hip_runtime.h>
#include <hip/hip_bf16.h>
#include <math.h>

#define BB 2
#define SS 2048
#define DD 1024
#define HH 16
#define HDIM 64

typedef unsigned short u16;
typedef __attribute__((ext_vector_type(8))) short bfrag;   // 8 bf16 = 4 VGPRs
typedef __attribute__((ext_vector_type(4))) float f32x4;

#define NEG_BIG (-1e30f)
// 1/sqrt(64) * log2(e): folded into Q so attention uses exp2 directly
#define QSCALE 0.18033688011112042f

__device__ __forceinline__ u16 f2u(float f) {
    unsigned int u = __builtin_bit_cast(unsigned int, f);
    u += 0x7fffu + ((u >> 16) & 1u);
    return (u16)(u >> 16);
}

__device__ __forceinline__ void async16(const u16* g, u16* l) {
    __builtin_amdgcn_global_load_lds((__attribute__((address_space(1))) void*)g,
                                     (__attribute__((address_space(3))) void*)l,
                                     16, 0, 0);
}

__device__ __forceinline__ f32x4 mfma16(bfrag a, bfrag b, f32x4 c) {
    return __builtin_amdgcn_mfma_f32_16x16x32_bf16(a, b, c, 0, 0, 0);
}

// ---------------------------------------------------------------------------
// prep: fused cvt_x + cvt_wT (r12 verbatim).
// ---------------------------------------------------------------------------
__global__ __launch_bounds__(256) void prep_k(
    const float* __restrict__ x,  u16* __restrict__ xb,
    const float* __restrict__ wq, const float* __restrict__ wk,
    const float* __restrict__ wv, const float* __restrict__ wo,
    u16* __restrict__ wT)
{
    const int id = blockIdx.x;
    const int t = threadIdx.x;
    if (id < 2048) {
        int i = (id * 256 + t) * 8;
        float4 a = *(const float4*)(x + i);
        float4 b = *(const float4*)(x + i + 4);
        u16 o[8] = { f2u(a.x), f2u(a.y), f2u(a.z), f2u(a.w),
                     f2u(b.x), f2u(b.y), f2u(b.z), f2u(b.w) };
        *(uint4*)(xb + i) = *(uint4*)o;
        return;
    }
    const int wid = id - 2048;
    const int z = wid >> 8;
    const int kt = wid & 15, nt = (wid >> 4) & 15;
    const float* w = (z == 0) ? wq : (z == 1) ? wk : (z == 2) ? wv : wo;
    u16* o = wT + (size_t)z * DD * DD;
    __shared__ __align__(16) u16 T[64][72];
    const int k0 = kt * 64, n0 = nt * 64;
    {
        int kr = t >> 2, nb = (t & 3) * 16;
        const float4* s4 = (const float4*)(w + (size_t)(k0 + kr) * DD + n0 + nb);
        #pragma unroll
        for (int jj = 0; jj < 4; ++jj) {
            float4 v = s4[jj];
            T[kr][nb + jj*4 + 0] = f2u(v.x);
            T[kr][nb + jj*4 + 1] = f2u(v.y);
            T[kr][nb + jj*4 + 2] = f2u(v.z);
            T[kr][nb + jj*4 + 3] = f2u(v.w);
        }
    }
    __syncthreads();
    {
        int nr = t >> 2, kb = (t & 3) * 16;
        u16 tmp[16];
        #pragma unroll
        for (int j = 0; j < 16; ++j) tmp[j] = T[kb + j][nr];
        *(uint4*)(o + (size_t)(n0 + nr) * DD + k0 + kb)     = ((uint4*)tmp)[0];
        *(uint4*)(o + (size_t)(n0 + nr) * DD + k0 + kb + 8) = ((uint4*)tmp)[1];
    }
}

// ===========================================================================
// QKV GEMM (r12 verbatim): BM=128, BN=64, BK=64 -> 1536 blocks.
// ===========================================================================
__global__ __launch_bounds__(256) void gemm_qkv_k(
    const u16* __restrict__ xb, const u16* __restrict__ wT,
    u16* __restrict__ Qo, u16* __restrict__ Ko, u16* __restrict__ Vt)
{
    const u16* wTz = wT + (size_t)blockIdx.z * DD * DD;
    const float osc = (blockIdx.z == 0) ? QSCALE : 1.0f;

    __shared__ __align__(16) u16 As[128 * 64];   // 16 KB
    __shared__ __align__(16) u16 Bs[64 * 64];    // 8 KB

    const int t = threadIdx.x;
    const int m0 = blockIdx.x * 128, n0 = blockIdx.y * 64;
    const int lane15 = t & 15, quad = (t >> 4) & 3, wave = t >> 6;
    const int wm = wave & 1, wn = wave >> 1;

    int arow[4], acol[4];
    #pragma unroll
    for (int i = 0; i < 4; ++i) {
        int c = t + i * 256;
        arow[i] = c >> 3;
        acol[i] = (c & 7) ^ (arow[i] & 7);
    }
    const int br0 = t >> 3,         bs0 = t & 7;
    const int br1 = (t + 256) >> 3, bs1 = (t + 256) & 7;
    const int bc0 = bs0 ^ (br0 & 7);
    const int bc1 = bs1 ^ (br1 & 7);
    const int ldb = (t & 192) * 8;

    int aoff[4][2], boff[2][2];
    #pragma unroll
    for (int mi = 0; mi < 4; ++mi) {
        int r = wm * 64 + mi * 16 + lane15;
        #pragma unroll
        for (int kh = 0; kh < 2; ++kh)
            aoff[mi][kh] = (r * 8 + ((kh * 4 + quad) ^ (r & 7))) * 8;
    }
    #pragma unroll
    for (int ni = 0; ni < 2; ++ni) {
        int r = wn * 32 + ni * 16 + lane15;
        #pragma unroll
        for (int kh = 0; kh < 2; ++kh)
            boff[ni][kh] = (r * 8 + ((kh * 4 + quad) ^ (r & 7))) * 8;
    }

    f32x4 acc[4][2];
    #pragma unroll
    for (int mi = 0; mi < 4; ++mi)
        #pragma unroll
        for (int ni = 0; ni < 2; ++ni)
            acc[mi][ni] = (f32x4){0.f, 0.f, 0.f, 0.f};

    for (int it = 0; it < 16; ++it) {
        const int k0 = it * 64;
        #pragma unroll
        for (int i = 0; i < 4; ++i)
            async16(xb + (size_t)(m0 + arow[i]) * DD + k0 + acol[i] * 8,
                    As + ldb + i * 2048);
        async16(wTz + (size_t)(n0 + br0) * DD + k0 + bc0 * 8, Bs + ldb);
        async16(wTz + (size_t)(n0 + br1) * DD + k0 + bc1 * 8, Bs + ldb + 2048);
        __syncthreads();
        #pragma unroll
        for (int kh = 0; kh < 2; ++kh) {
            bfrag av[4], bv[2];
            #pragma unroll
            for (int mi = 0; mi < 4; ++mi) av[mi] = *(const bfrag*)(As + aoff[mi][kh]);
            #pragma unroll
            for (int ni = 0; ni < 2; ++ni) bv[ni] = *(const bfrag*)(Bs + boff[ni][kh]);
            #pragma unroll
            for (int mi = 0; mi < 4; ++mi)
                #pragma unroll
                for (int ni = 0; ni < 2; ++ni)
                    acc[mi][ni] = mfma16(av[mi], bv[ni], acc[mi][ni]);
        }
        __syncthreads();
    }

    const int h = n0 >> 6;
    const int bq = m0 >> 11;
    const int ms = m0 & (SS - 1);

    if (blockIdx.z != 2) {
        u16* out = (blockIdx.z == 0) ? Qo : Ko;
        u16* dst = out + (((size_t)(bq * HH + h)) * SS) * HDIM;
        #pragma unroll
        for (int mi = 0; mi < 4; ++mi) {
            #pragma unroll
            for (int r = 0; r < 4; ++r) {
                int s = ms + wm * 64 + mi * 16 + quad * 4 + r;
                #pragma unroll
                for (int ni = 0; ni < 2; ++ni) {
                    int hd = wn * 32 + ni * 16 + lane15;
                    dst[(size_t)s * HDIM + hd] = f2u(acc[mi][ni][r] * osc);
                }
            }
        }
    } else {
        u16* T = As;
        __syncthreads();
        #pragma unroll
        for (int mi = 0; mi < 4; ++mi)
            #pragma unroll
            for (int r = 0; r < 4; ++r) {
                int ml = wm * 64 + mi * 16 + quad * 4 + r;
                #pragma unroll
                for (int ni = 0; ni < 2; ++ni) {
                    int nl = wn * 32 + ni * 16 + lane15;
                    T[nl * 128 + (ml ^ ((nl & 7) << 4))] = f2u(acc[mi][ni][r]);
                }
            }
        __syncthreads();
        u16* dst = Vt + ((size_t)(bq * HH + h)) * (HDIM * SS);
        #pragma unroll
        for (int i = 0; i < 4; ++i) {
            int c = t + i * 256;
            int row = c >> 4;
            int mb  = (c & 15) * 8;
            uint4 val = *(const uint4*)&T[row * 128 + (mb ^ ((row & 7) << 4))];
            *(uint4*)(dst + (size_t)row * SS + ms + mb) = val;
        }
    }
}

// ---------------------------------------------------------------------------
// Out projection (r14): BM=64, BN=64, BK=128 (two 64-halves, same swizzle)
// -> 16 MFMA/barrier, 8 iters, LDS 32KB. Fused bias, fp32 out.
// ---------------------------------------------------------------------------
__global__ __launch_bounds__(256) void gemm_out_k(
    const u16* __restrict__ ctxb, const u16* __restrict__ woT,
    const float* __restrict__ bo, float* __restrict__ out)
{
    __shared__ __align__(16) u16 As[2][4096];    // [k-half][64x64]
    __shared__ __align__(16) u16 Bs[2][4096];

    const int t = threadIdx.x;
    const int m0 = blockIdx.x * 64, n0 = blockIdx.y * 64;
    const int lane15 = t & 15, quad = (t >> 4) & 3, wave = t >> 6;
    const int wm = wave & 1, wn = wave >> 1;

    const int br0 = t >> 3,         bs0 = t & 7;
    const int br1 = (t + 256) >> 3, bs1 = (t + 256) & 7;
    const int bc0 = bs0 ^ (br0 & 7);
    const int bc1 = bs1 ^ (br1 & 7);
    const int ldb = (t & 192) * 8;

    int aoff[2][2], boff[2][2];
    #pragma unroll
    for (int mi = 0; mi < 2; ++mi) {
        int r = wm * 32 + mi * 16 + lane15;
        #pragma unroll
        for (int kh = 0; kh < 2; ++kh)
            aoff[mi][kh] = (r * 8 + ((kh * 4 + quad) ^ (r & 7))) * 8;
    }
    #pragma unroll
    for (int ni = 0; ni < 2; ++ni) {
        int r = wn * 32 + ni * 16 + lane15;
        #pragma unroll
        for (int kh = 0; kh < 2; ++kh)
            boff[ni][kh] = (r * 8 + ((kh * 4 + quad) ^ (r & 7))) * 8;
    }

    f32x4 acc[2][2];
    #pragma unroll
    for (int mi = 0; mi < 2; ++mi)
        #pragma unroll
        for (int ni = 0; ni < 2; ++ni)
            acc[mi][ni] = (f32x4){0.f, 0.f, 0.f, 0.f};

    for (int it = 0; it < 8; ++it) {
        const int k0 = it * 128;
        #pragma unroll
        for (int hh = 0; hh < 2; ++hh) {
            const int kh64 = k0 + hh * 64;
            async16(ctxb + (size_t)(m0 + br0) * DD + kh64 + bc0 * 8, &As[hh][ldb]);
            async16(ctxb + (size_t)(m0 + br1) * DD + kh64 + bc1 * 8, &As[hh][ldb + 2048]);
            async16(woT  + (size_t)(n0 + br0) * DD + kh64 + bc0 * 8, &Bs[hh][ldb]);
            async16(woT  + (size_t)(n0 + br1) * DD + kh64 + bc1 * 8, &Bs[hh][ldb + 2048]);
        }
        __syncthreads();
        #pragma unroll
        for (int hh = 0; hh < 2; ++hh) {
            #pragma unroll
            for (int kh = 0; kh < 2; ++kh) {
                bfrag av[2], bv[2];
                #pragma unroll
                for (int mi = 0; mi < 2; ++mi) av[mi] = *(const bfrag*)&As[hh][aoff[mi][kh]];
                #pragma unroll
                for (int ni = 0; ni < 2; ++ni) bv[ni] = *(const bfrag*)&Bs[hh][boff[ni][kh]];
                #pragma unroll
                for (int mi = 0; mi < 2; ++mi)
                    #pragma unroll
                    for (int ni = 0; ni < 2; ++ni)
                        acc[mi][ni] = mfma16(av[mi], bv[ni], acc[mi][ni]);
            }
        }
        __syncthreads();
    }

    float bias[2];
    #pragma unroll
    for (int ni = 0; ni < 2; ++ni)
        bias[ni] = bo[n0 + wn * 32 + ni * 16 + lane15];

    #pragma unroll
    for (int mi = 0; mi < 2; ++mi) {
        #pragma unroll
        for (int r = 0; r < 4; ++r) {
            int m = m0 + wm * 32 + mi * 16 + quad * 4 + r;
            #pragma unroll
            for (int ni = 0; ni < 2; ++ni) {
                int n = n0 + wn * 32 + ni * 16 + lane15;
                out[(size_t)m * DD + n] = acc[mi][ni][r] + bias[ni];
            }
        }
    }
}

// ===========================================================================
// MFMA flash attention (r12 verbatim — empirically best: descending qt,
// 40KB LDS -> 4 blocks/CU). Fixed-max softmax, exp2, Q-frags in registers,
// Ps aliases Qs, K/V double-buffered, 1 barrier/iter.
// Dispatch-mapping experiments (r13 pairing, r14 balanced interleave) both
// regressed — do not re-theorize dispatch order without new evidence.
// ===========================================================================
__global__ __launch_bounds__(256, 4) void attn_k(
    const u16* __restrict__ Q, const u16* __restrict__ K,
    const u16* __restrict__ Vt, u16* __restrict__ ctx)
{
    __shared__ __align__(16) u16 QP[64 * 64];
    __shared__ __align__(16) u16 Ks[2][64 * 64];
    __shared__ __align__(16) u16 Vs[2][64 * 64];
    const int t = threadIdx.x;
    const int lane15 = t & 15, quad = (t >> 4) & 3, wave = t >> 6;
    const int bh = blockIdx.x;
    const int qt = (int)(gridDim.y - 1) - (int)blockIdx.y;   // descending qt
    const int q0 = qt * 64;
    const int b = bh >> 4, h = bh & 15;
    const u16* Qb = Q  + (size_t)bh * SS * HDIM;
    const u16* Kb = K  + (size_t)bh * SS * HDIM;
    const u16* Vb = Vt + (size_t)bh * HDIM * SS;
    const int kr0 = t >> 3,         ks0 = t & 7;
    const int kr1 = (t + 256) >> 3, ks1 = (t + 256) & 7;
    const int kc0 = ks0 ^ (kr0 & 7);
    const int kc1 = ks1 ^ (kr1 & 7);
    const int ldst = (t & 192) * 8;
    async16(Qb + (size_t)(q0 + kr0) * HDIM + kc0 * 8, QP + ldst);
    async16(Qb + (size_t)(q0 + kr1) * HDIM + kc1 * 8, QP + ldst + 2048);
    async16(Kb + (size_t)kr0 * HDIM + kc0 * 8, &Ks[0][ldst]);
    async16(Kb + (size_t)kr1 * HDIM + kc1 * 8, &Ks[0][ldst + 2048]);
    async16(Vb + (size_t)kr0 * SS + kc0 * 8, &Vs[0][ldst]);
    async16(Vb + (size_t)kr1 * SS + kc1 * 8, &Vs[0][ldst + 2048]);
    const int qrow = wave * 16 + lane15;
    int qoff[2], koff[4][2];
    #pragma unroll
    for (int kh = 0; kh < 2; ++kh)
        qoff[kh] = (qrow * 8 + ((kh * 4 + quad) ^ (qrow & 7))) * 8;
    #pragma unroll
    for (int ni = 0; ni < 4; ++ni)
        #pragma unroll
        for (int kh = 0; kh < 2; ++kh) {
            int row = ni * 16 + lane15;
            koff[ni][kh] = (row * 8 + ((kh * 4 + quad) ^ (row & 7))) * 8;
        }
    __syncthreads();
    bfrag aq[2];
    aq[0] = *(const bfrag*)(QP + qoff[0]);
    aq[1] = *(const bfrag*)(QP + qoff[1]);
    __syncthreads();
    f32x4 acc_o[4];
    float rsum[4] = {0.f, 0.f, 0.f, 0.f};
    #pragma unroll
    for (int nd = 0; nd < 4; ++nd) acc_o[nd] = (f32x4){0.f, 0.f, 0.f, 0.f};
    const int qgb = q0 + wave * 16 + quad * 4;
    for (int kt = 0; kt <= qt; ++kt) {
        if (kt < qt) {
            const int nv0 = (kt + 1) * 64;
            const int pb = (kt + 1) & 1;
            async16(Kb + (size_t)(nv0 + kr0) * HDIM + kc0 * 8, &Ks[pb][ldst]);
            async16(Kb + (size_t)(nv0 + kr1) * HDIM + kc1 * 8, &Ks[pb][ldst + 2048]);
            async16(Vb + (size_t)kr0 * SS + nv0 + kc0 * 8, &Vs[pb][ldst]);
            async16(Vb + (size_t)kr1 * SS + nv0 + kc1 * 8, &Vs[pb][ldst + 2048]);
        }
        const int cb = kt & 1;
        const int kv0 = kt * 64;
        f32x4 s_acc[4];
        #pragma unroll
        for (int ni = 0; ni < 4; ++ni) s_acc[ni] = (f32x4){0.f, 0.f, 0.f, 0.f};
        #pragma unroll
        for (int kh = 0; kh < 2; ++kh)
            #pragma unroll
            for (int ni = 0; ni < 4; ++ni)
                s_acc[ni] = mfma16(aq[kh], *(const bfrag*)&Ks[cb][koff[ni][kh]], s_acc[ni]);
        const bool diag = (kt == qt);
        #pragma unroll
        for (int ni = 0; ni < 4; ++ni) {
            int kvg = kv0 + ni * 16 + lane15;
            #pragma unroll
            for (int r = 0; r < 4; ++r) {
                float v = s_acc[ni][r];
                if (diag && (kvg > qgb + r)) v = NEG_BIG;
                float pw = exp2f(v);
                unsigned pu = __builtin_bit_cast(unsigned, pw);
                rsum[r] += __builtin_bit_cast(float, pu & 0xffff0000u);
                int row = wave * 16 + quad * 4 + r;
                int col = ni * 16 + lane15;
                QP[(row * 8 + ((col >> 3) ^ (row & 7))) * 8 + (col & 7)] = (u16)(pu >> 16);
            }
        }
        #pragma unroll
        for (int kh = 0; kh < 2; ++kh) {
            bfrag ap = *(const bfrag*)(QP + qoff[kh]);
            #pragma unroll
            for (int nd = 0; nd < 4; ++nd)
                acc_o[nd] = mfma16(ap, *(const bfrag*)&Vs[cb][koff[nd][kh]], acc_o[nd]);
        }
        __syncthreads();
    }
    #pragma unroll
    for (int off = 1; off < 16; off <<= 1)
        #pragma unroll
        for (int r = 0; r < 4; ++r)
            rsum[r] += __shfl_xor(rsum[r], off, 64);
    #pragma unroll
    for (int r = 0; r < 4; ++r) {
        float inv = 1.f / rsum[r];
        int srow = q0 + wave * 16 + quad * 4 + r;
        size_t base = ((size_t)b * SS + srow) * DD + h * HDIM;
        #pragma unroll
        for (int nd = 0; nd < 4; ++nd)
            ctx[base + nd * 16 + lane15] = f2u(acc_o[nd][r] * inv);
    }
}

extern "C" void kernel_launch(void* const* d_in, const int* in_sizes, int n_in,
                              void* d_out, int out_size, void* d_ws, size_t ws_size,
                              hipStream_t stream) {
    const float* x  = (const float*)d_in[0];
    const float* wq = (const float*)d_in[1];
    const float* wk = (const float*)d_in[2];
    const float* wv = (const float*)d_in[3];
    const float* wo = (const float*)d_in[4];
    const float* bo = (const float*)d_in[5];
    float* out = (float*)d_out;

    char* ws = (char*)d_ws;
    const size_t MB8 = (size_t)8 * 1024 * 1024;
    u16* xb  = (u16*)(ws);             // 8MB; ctx reuses after qkv consumption
    u16* wT  = (u16*)(ws + MB8);       // 8MB
    u16* Qb  = (u16*)(ws + 2 * MB8);   // 8MB
    u16* Kb  = (u16*)(ws + 3 * MB8);   // 8MB
    u16* Vt  = (u16*)(ws + 4 * MB8);   // 8MB
    u16* ctxb = xb;

    prep_k    <<<3072, 256, 0, stream>>>(x, xb, wq, wk, wv, wo, wT);
    gemm_qkv_k<<<dim3(32, 16, 3), 256, 0, stream>>>(xb, wT, Qb, Kb, Vt);
    attn_k    <<<dim3(32, 32), 256, 0, stream>>>(Qb, Kb, Vt, ctxb);
    gemm_out_k<<<dim3(64, 16), 256, 0, stream>>>(ctxb, wT + (size_t)3 * DD * DD, bo, out);
}

// Round 16
// 171.970 us; speedup vs baseline: 1.2255x; 1.0243x over previous
//
#include <hip/hip_runtime.h>
#include <hip/hip_bf16.h>
#include <math.h>

#define BB 2
#define SS 2048
#define DD 1024
#define HH 16
#define HDIM 64

typedef unsigned short u16;
typedef __attribute__((ext_vector_type(8))) short bfrag;   // 8 bf16 = 4 VGPRs
typedef __attribute__((ext_vector_type(4))) float f32x4;

#define NEG_BIG (-1e30f)
// 1/sqrt(64) * log2(e): folded into Q so attention uses exp2 directly
#define QSCALE 0.18033688011112042f

__device__ __forceinline__ u16 f2u(float f) {
    unsigned int u = __builtin_bit_cast(unsigned int, f);
    u += 0x7fffu + ((u >> 16) & 1u);
    return (u16)(u >> 16);
}

__device__ __forceinline__ void async16(const u16* g, u16* l) {
    __builtin_amdgcn_global_load_lds((__attribute__((address_space(1))) void*)g,
                                     (__attribute__((address_space(3))) void*)l,
                                     16, 0, 0);
}

__device__ __forceinline__ f32x4 mfma16(bfrag a, bfrag b, f32x4 c) {
    return __builtin_amdgcn_mfma_f32_16x16x32_bf16(a, b, c, 0, 0, 0);
}

// ---------------------------------------------------------------------------
// prep: fused cvt_x + cvt_wT (r12 verbatim).
// ---------------------------------------------------------------------------
__global__ __launch_bounds__(256) void prep_k(
    const float* __restrict__ x,  u16* __restrict__ xb,
    const float* __restrict__ wq, const float* __restrict__ wk,
    const float* __restrict__ wv, const float* __restrict__ wo,
    u16* __restrict__ wT)
{
    const int id = blockIdx.x;
    const int t = threadIdx.x;
    if (id < 2048) {
        int i = (id * 256 + t) * 8;
        float4 a = *(const float4*)(x + i);
        float4 b = *(const float4*)(x + i + 4);
        u16 o[8] = { f2u(a.x), f2u(a.y), f2u(a.z), f2u(a.w),
                     f2u(b.x), f2u(b.y), f2u(b.z), f2u(b.w) };
        *(uint4*)(xb + i) = *(uint4*)o;
        return;
    }
    const int wid = id - 2048;
    const int z = wid >> 8;
    const int kt = wid & 15, nt = (wid >> 4) & 15;
    const float* w = (z == 0) ? wq : (z == 1) ? wk : (z == 2) ? wv : wo;
    u16* o = wT + (size_t)z * DD * DD;
    __shared__ __align__(16) u16 T[64][72];
    const int k0 = kt * 64, n0 = nt * 64;
    {
        int kr = t >> 2, nb = (t & 3) * 16;
        const float4* s4 = (const float4*)(w + (size_t)(k0 + kr) * DD + n0 + nb);
        #pragma unroll
        for (int jj = 0; jj < 4; ++jj) {
            float4 v = s4[jj];
            T[kr][nb + jj*4 + 0] = f2u(v.x);
            T[kr][nb + jj*4 + 1] = f2u(v.y);
            T[kr][nb + jj*4 + 2] = f2u(v.z);
            T[kr][nb + jj*4 + 3] = f2u(v.w);
        }
    }
    __syncthreads();
    {
        int nr = t >> 2, kb = (t & 3) * 16;
        u16 tmp[16];
        #pragma unroll
        for (int j = 0; j < 16; ++j) tmp[j] = T[kb + j][nr];
        *(uint4*)(o + (size_t)(n0 + nr) * DD + k0 + kb)     = ((uint4*)tmp)[0];
        *(uint4*)(o + (size_t)(n0 + nr) * DD + k0 + kb + 8) = ((uint4*)tmp)[1];
    }
}

// ===========================================================================
// QKV GEMM (r12 verbatim): BM=128, BN=64, BK=64 -> 1536 blocks.
// ===========================================================================
__global__ __launch_bounds__(256) void gemm_qkv_k(
    const u16* __restrict__ xb, const u16* __restrict__ wT,
    u16* __restrict__ Qo, u16* __restrict__ Ko, u16* __restrict__ Vt)
{
    const u16* wTz = wT + (size_t)blockIdx.z * DD * DD;
    const float osc = (blockIdx.z == 0) ? QSCALE : 1.0f;

    __shared__ __align__(16) u16 As[128 * 64];   // 16 KB
    __shared__ __align__(16) u16 Bs[64 * 64];    // 8 KB

    const int t = threadIdx.x;
    const int m0 = blockIdx.x * 128, n0 = blockIdx.y * 64;
    const int lane15 = t & 15, quad = (t >> 4) & 3, wave = t >> 6;
    const int wm = wave & 1, wn = wave >> 1;

    int arow[4], acol[4];
    #pragma unroll
    for (int i = 0; i < 4; ++i) {
        int c = t + i * 256;
        arow[i] = c >> 3;
        acol[i] = (c & 7) ^ (arow[i] & 7);
    }
    const int br0 = t >> 3,         bs0 = t & 7;
    const int br1 = (t + 256) >> 3, bs1 = (t + 256) & 7;
    const int bc0 = bs0 ^ (br0 & 7);
    const int bc1 = bs1 ^ (br1 & 7);
    const int ldb = (t & 192) * 8;

    int aoff[4][2], boff[2][2];
    #pragma unroll
    for (int mi = 0; mi < 4; ++mi) {
        int r = wm * 64 + mi * 16 + lane15;
        #pragma unroll
        for (int kh = 0; kh < 2; ++kh)
            aoff[mi][kh] = (r * 8 + ((kh * 4 + quad) ^ (r & 7))) * 8;
    }
    #pragma unroll
    for (int ni = 0; ni < 2; ++ni) {
        int r = wn * 32 + ni * 16 + lane15;
        #pragma unroll
        for (int kh = 0; kh < 2; ++kh)
            boff[ni][kh] = (r * 8 + ((kh * 4 + quad) ^ (r & 7))) * 8;
    }

    f32x4 acc[4][2];
    #pragma unroll
    for (int mi = 0; mi < 4; ++mi)
        #pragma unroll
        for (int ni = 0; ni < 2; ++ni)
            acc[mi][ni] = (f32x4){0.f, 0.f, 0.f, 0.f};

    for (int it = 0; it < 16; ++it) {
        const int k0 = it * 64;
        #pragma unroll
        for (int i = 0; i < 4; ++i)
            async16(xb + (size_t)(m0 + arow[i]) * DD + k0 + acol[i] * 8,
                    As + ldb + i * 2048);
        async16(wTz + (size_t)(n0 + br0) * DD + k0 + bc0 * 8, Bs + ldb);
        async16(wTz + (size_t)(n0 + br1) * DD + k0 + bc1 * 8, Bs + ldb + 2048);
        __syncthreads();
        #pragma unroll
        for (int kh = 0; kh < 2; ++kh) {
            bfrag av[4], bv[2];
            #pragma unroll
            for (int mi = 0; mi < 4; ++mi) av[mi] = *(const bfrag*)(As + aoff[mi][kh]);
            #pragma unroll
            for (int ni = 0; ni < 2; ++ni) bv[ni] = *(const bfrag*)(Bs + boff[ni][kh]);
            #pragma unroll
            for (int mi = 0; mi < 4; ++mi)
                #pragma unroll
                for (int ni = 0; ni < 2; ++ni)
                    acc[mi][ni] = mfma16(av[mi], bv[ni], acc[mi][ni]);
        }
        __syncthreads();
    }

    const int h = n0 >> 6;
    const int bq = m0 >> 11;
    const int ms = m0 & (SS - 1);

    if (blockIdx.z != 2) {
        u16* out = (blockIdx.z == 0) ? Qo : Ko;
        u16* dst = out + (((size_t)(bq * HH + h)) * SS) * HDIM;
        #pragma unroll
        for (int mi = 0; mi < 4; ++mi) {
            #pragma unroll
            for (int r = 0; r < 4; ++r) {
                int s = ms + wm * 64 + mi * 16 + quad * 4 + r;
                #pragma unroll
                for (int ni = 0; ni < 2; ++ni) {
                    int hd = wn * 32 + ni * 16 + lane15;
                    dst[(size_t)s * HDIM + hd] = f2u(acc[mi][ni][r] * osc);
                }
            }
        }
    } else {
        u16* T = As;
        __syncthreads();
        #pragma unroll
        for (int mi = 0; mi < 4; ++mi)
            #pragma unroll
            for (int r = 0; r < 4; ++r) {
                int ml = wm * 64 + mi * 16 + quad * 4 + r;
                #pragma unroll
                for (int ni = 0; ni < 2; ++ni) {
                    int nl = wn * 32 + ni * 16 + lane15;
                    T[nl * 128 + (ml ^ ((nl & 7) << 4))] = f2u(acc[mi][ni][r]);
                }
            }
        __syncthreads();
        u16* dst = Vt + ((size_t)(bq * HH + h)) * (HDIM * SS);
        #pragma unroll
        for (int i = 0; i < 4; ++i) {
            int c = t + i * 256;
            int row = c >> 4;
            int mb  = (c & 15) * 8;
            uint4 val = *(const uint4*)&T[row * 128 + (mb ^ ((row & 7) << 4))];
            *(uint4*)(dst + (size_t)row * SS + ms + mb) = val;
        }
    }
}

// ---------------------------------------------------------------------------
// Out projection (r14): BM=64, BN=64, BK=128 (two 64-halves, same swizzle)
// -> 16 MFMA/barrier, 8 iters, LDS 32KB. Fused bias, fp32 out.
// ---------------------------------------------------------------------------
__global__ __launch_bounds__(256) void gemm_out_k(
    const u16* __restrict__ ctxb, const u16* __restrict__ woT,
    const float* __restrict__ bo, float* __restrict__ out)
{
    __shared__ __align__(16) u16 As[2][4096];    // [k-half][64x64]
    __shared__ __align__(16) u16 Bs[2][4096];

    const int t = threadIdx.x;
    const int m0 = blockIdx.x * 64, n0 = blockIdx.y * 64;
    const int lane15 = t & 15, quad = (t >> 4) & 3, wave = t >> 6;
    const int wm = wave & 1, wn = wave >> 1;

    const int br0 = t >> 3,         bs0 = t & 7;
    const int br1 = (t + 256) >> 3, bs1 = (t + 256) & 7;
    const int bc0 = bs0 ^ (br0 & 7);
    const int bc1 = bs1 ^ (br1 & 7);
    const int ldb = (t & 192) * 8;

    int aoff[2][2], boff[2][2];
    #pragma unroll
    for (int mi = 0; mi < 2; ++mi) {
        int r = wm * 32 + mi * 16 + lane15;
        #pragma unroll
        for (int kh = 0; kh < 2; ++kh)
            aoff[mi][kh] = (r * 8 + ((kh * 4 + quad) ^ (r & 7))) * 8;
    }
    #pragma unroll
    for (int ni = 0; ni < 2; ++ni) {
        int r = wn * 32 + ni * 16 + lane15;
        #pragma unroll
        for (int kh = 0; kh < 2; ++kh)
            boff[ni][kh] = (r * 8 + ((kh * 4 + quad) ^ (r & 7))) * 8;
    }

    f32x4 acc[2][2];
    #pragma unroll
    for (int mi = 0; mi < 2; ++mi)
        #pragma unroll
        for (int ni = 0; ni < 2; ++ni)
            acc[mi][ni] = (f32x4){0.f, 0.f, 0.f, 0.f};

    for (int it = 0; it < 8; ++it) {
        const int k0 = it * 128;
        #pragma unroll
        for (int hh = 0; hh < 2; ++hh) {
            const int kh64 = k0 + hh * 64;
            async16(ctxb + (size_t)(m0 + br0) * DD + kh64 + bc0 * 8, &As[hh][ldb]);
            async16(ctxb + (size_t)(m0 + br1) * DD + kh64 + bc1 * 8, &As[hh][ldb + 2048]);
            async16(woT  + (size_t)(n0 + br0) * DD + kh64 + bc0 * 8, &Bs[hh][ldb]);
            async16(woT  + (size_t)(n0 + br1) * DD + kh64 + bc1 * 8, &Bs[hh][ldb + 2048]);
        }
        __syncthreads();
        #pragma unroll
        for (int hh = 0; hh < 2; ++hh) {
            #pragma unroll
            for (int kh = 0; kh < 2; ++kh) {
                bfrag av[2], bv[2];
                #pragma unroll
                for (int mi = 0; mi < 2; ++mi) av[mi] = *(const bfrag*)&As[hh][aoff[mi][kh]];
                #pragma unroll
                for (int ni = 0; ni < 2; ++ni) bv[ni] = *(const bfrag*)&Bs[hh][boff[ni][kh]];
                #pragma unroll
                for (int mi = 0; mi < 2; ++mi)
                    #pragma unroll
                    for (int ni = 0; ni < 2; ++ni)
                        acc[mi][ni] = mfma16(av[mi], bv[ni], acc[mi][ni]);
            }
        }
        __syncthreads();
    }

    float bias[2];
    #pragma unroll
    for (int ni = 0; ni < 2; ++ni)
        bias[ni] = bo[n0 + wn * 32 + ni * 16 + lane15];

    #pragma unroll
    for (int mi = 0; mi < 2; ++mi) {
        #pragma unroll
        for (int r = 0; r < 4; ++r) {
            int m = m0 + wm * 32 + mi * 16 + quad * 4 + r;
            #pragma unroll
            for (int ni = 0; ni < 2; ++ni) {
                int n = n0 + wn * 32 + ni * 16 + lane15;
                out[(size_t)m * DD + n] = acc[mi][ni][r] + bias[ni];
            }
        }
    }
}

// ===========================================================================
// MFMA flash attention (r12 structure). NEW: row-sum via MFMA with a constant
// all-ones B fragment — acc_s = P x ones accumulates the EXACT bf16 P values
// read from LDS (numerator == denominator terms), deleting per-iter rsum adds,
// the truncation-and, and the final shfl-xor reduction.
// ===========================================================================
__global__ __launch_bounds__(256, 4) void attn_k(
    const u16* __restrict__ Q, const u16* __restrict__ K,
    const u16* __restrict__ Vt, u16* __restrict__ ctx)
{
    __shared__ __align__(16) u16 QP[64 * 64];
    __shared__ __align__(16) u16 Ks[2][64 * 64];
    __shared__ __align__(16) u16 Vs[2][64 * 64];
    const int t = threadIdx.x;
    const int lane15 = t & 15, quad = (t >> 4) & 3, wave = t >> 6;
    const int bh = blockIdx.x;
    const int qt = (int)(gridDim.y - 1) - (int)blockIdx.y;   // descending qt
    const int q0 = qt * 64;
    const int b = bh >> 4, h = bh & 15;
    const u16* Qb = Q  + (size_t)bh * SS * HDIM;
    const u16* Kb = K  + (size_t)bh * SS * HDIM;
    const u16* Vb = Vt + (size_t)bh * HDIM * SS;
    const int kr0 = t >> 3,         ks0 = t & 7;
    const int kr1 = (t + 256) >> 3, ks1 = (t + 256) & 7;
    const int kc0 = ks0 ^ (kr0 & 7);
    const int kc1 = ks1 ^ (kr1 & 7);
    const int ldst = (t & 192) * 8;
    async16(Qb + (size_t)(q0 + kr0) * HDIM + kc0 * 8, QP + ldst);
    async16(Qb + (size_t)(q0 + kr1) * HDIM + kc1 * 8, QP + ldst + 2048);
    async16(Kb + (size_t)kr0 * HDIM + kc0 * 8, &Ks[0][ldst]);
    async16(Kb + (size_t)kr1 * HDIM + kc1 * 8, &Ks[0][ldst + 2048]);
    async16(Vb + (size_t)kr0 * SS + kc0 * 8, &Vs[0][ldst]);
    async16(Vb + (size_t)kr1 * SS + kc1 * 8, &Vs[0][ldst + 2048]);
    const int qrow = wave * 16 + lane15;
    int qoff[2], koff[4][2];
    #pragma unroll
    for (int kh = 0; kh < 2; ++kh)
        qoff[kh] = (qrow * 8 + ((kh * 4 + quad) ^ (qrow & 7))) * 8;
    #pragma unroll
    for (int ni = 0; ni < 4; ++ni)
        #pragma unroll
        for (int kh = 0; kh < 2; ++kh) {
            int row = ni * 16 + lane15;
            koff[ni][kh] = (row * 8 + ((kh * 4 + quad) ^ (row & 7))) * 8;
        }
    __syncthreads();
    bfrag aq[2];
    aq[0] = *(const bfrag*)(QP + qoff[0]);
    aq[1] = *(const bfrag*)(QP + qoff[1]);
    __syncthreads();

    bfrag bones;                       // bf16 1.0 x8 (B-operand from VGPRs)
    #pragma unroll
    for (int i = 0; i < 8; ++i) bones[i] = (short)0x3f80;

    f32x4 acc_o[4];
    f32x4 acc_s = (f32x4){0.f, 0.f, 0.f, 0.f};   // row sums via MFMA
    #pragma unroll
    for (int nd = 0; nd < 4; ++nd) acc_o[nd] = (f32x4){0.f, 0.f, 0.f, 0.f};
    const int qgb = q0 + wave * 16 + quad * 4;
    for (int kt = 0; kt <= qt; ++kt) {
        if (kt < qt) {
            const int nv0 = (kt + 1) * 64;
            const int pb = (kt + 1) & 1;
            async16(Kb + (size_t)(nv0 + kr0) * HDIM + kc0 * 8, &Ks[pb][ldst]);
            async16(Kb + (size_t)(nv0 + kr1) * HDIM + kc1 * 8, &Ks[pb][ldst + 2048]);
            async16(Vb + (size_t)kr0 * SS + nv0 + kc0 * 8, &Vs[pb][ldst]);
            async16(Vb + (size_t)kr1 * SS + nv0 + kc1 * 8, &Vs[pb][ldst + 2048]);
        }
        const int cb = kt & 1;
        const int kv0 = kt * 64;
        f32x4 s_acc[4];
        #pragma unroll
        for (int ni = 0; ni < 4; ++ni) s_acc[ni] = (f32x4){0.f, 0.f, 0.f, 0.f};
        #pragma unroll
        for (int kh = 0; kh < 2; ++kh)
            #pragma unroll
            for (int ni = 0; ni < 4; ++ni)
                s_acc[ni] = mfma16(aq[kh], *(const bfrag*)&Ks[cb][koff[ni][kh]], s_acc[ni]);
        const bool diag = (kt == qt);
        #pragma unroll
        for (int ni = 0; ni < 4; ++ni) {
            int kvg = kv0 + ni * 16 + lane15;
            #pragma unroll
            for (int r = 0; r < 4; ++r) {
                float v = s_acc[ni][r];
                if (diag && (kvg > qgb + r)) v = NEG_BIG;
                unsigned pu = __builtin_bit_cast(unsigned, exp2f(v));
                int row = wave * 16 + quad * 4 + r;
                int col = ni * 16 + lane15;
                QP[(row * 8 + ((col >> 3) ^ (row & 7))) * 8 + (col & 7)] = (u16)(pu >> 16);
            }
        }
        #pragma unroll
        for (int kh = 0; kh < 2; ++kh) {
            bfrag ap = *(const bfrag*)(QP + qoff[kh]);
            #pragma unroll
            for (int nd = 0; nd < 4; ++nd)
                acc_o[nd] = mfma16(ap, *(const bfrag*)&Vs[cb][koff[nd][kh]], acc_o[nd]);
            acc_s = mfma16(ap, bones, acc_s);   // row sum of the SAME bf16 P
        }
        __syncthreads();
    }
    #pragma unroll
    for (int r = 0; r < 4; ++r) {
        float inv = 1.f / acc_s[r];            // replicated across col group
        int srow = q0 + wave * 16 + quad * 4 + r;
        size_t base = ((size_t)b * SS + srow) * DD + h * HDIM;
        #pragma unroll
        for (int nd = 0; nd < 4; ++nd)
            ctx[base + nd * 16 + lane15] = f2u(acc_o[nd][r] * inv);
    }
}

extern "C" void kernel_launch(void* const* d_in, const int* in_sizes, int n_in,
                              void* d_out, int out_size, void* d_ws, size_t ws_size,
                              hipStream_t stream) {
    const float* x  = (const float*)d_in[0];
    const float* wq = (const float*)d_in[1];
    const float* wk = (const float*)d_in[2];
    const float* wv = (const float*)d_in[3];
    const float* wo = (const float*)d_in[4];
    const float* bo = (const float*)d_in[5];
    float* out = (float*)d_out;

    char* ws = (char*)d_ws;
    const size_t MB8 = (size_t)8 * 1024 * 1024;
    u16* xb  = (u16*)(ws);             // 8MB; ctx reuses after qkv consumption
    u16* wT  = (u16*)(ws + MB8);       // 8MB
    u16* Qb  = (u16*)(ws + 2 * MB8);   // 8MB
    u16* Kb  = (u16*)(ws + 3 * MB8);   // 8MB
    u16* Vt  = (u16*)(ws + 4 * MB8);   // 8MB
    u16* ctxb = xb;

    prep_k    <<<3072, 256, 0, stream>>>(x, xb, wq, wk, wv, wo, wT);
    gemm_qkv_k<<<dim3(32, 16, 3), 256, 0, stream>>>(xb, wT, Qb, Kb, Vt);
    attn_k    <<<dim3(32, 32), 256, 0, stream>>>(Qb, Kb, Vt, ctxb);
    gemm_out_k<<<dim3(64, 16), 256, 0, stream>>>(ctxb, wT + (size_t)3 * DD * DD, bo, out);
}